// Round 6
// baseline (378.353 us; speedup 1.0000x reference)
//
#include <hip/hip_runtime.h>

typedef unsigned int u32;
typedef unsigned long long u64;

#define NB 10
#define BLOCKS 2048
#define TPB 256
#define F4_PER_BLOCK 4096   // 2^23 float4 / 2048 blocks

// ws layout: bin b occupies its own 128-B cache line at u32 index 32*b:
//   [32b+0 .. 32b+1] = u64 conf fixed-point sum, [32b+2] = count, [32b+3] = positives
// probe scratch: u32 index 320..351 (diagnostic only, never read by finalize)
__global__ void rd_zero_ws(u32* __restrict__ ws) {
    int t = threadIdx.x;
    if (t < 320) ws[t] = 0u;
}

// ---------------- DIAGNOSTIC PROBE: same loads as rd_hist, ~2 VALU/elem ----------
__global__ __launch_bounds__(TPB) void rd_probe(const uint4* __restrict__ a,
                                                const uint4* __restrict__ b,
                                                u32* __restrict__ ws, long long n4) {
    long long seg = (long long)blockIdx.x * F4_PER_BLOCK;
    u32 acc = 0;
    if (seg + F4_PER_BLOCK <= n4) {
        long long base = seg + threadIdx.x;
        #pragma unroll
        for (int s = 0; s < 4; ++s) {
            long long o = base + (long long)s * (4 * TPB);
            uint4 x0 = a[o], x1 = a[o + TPB], x2 = a[o + 2 * TPB], x3 = a[o + 3 * TPB];
            uint4 y0 = b[o], y1 = b[o + TPB], y2 = b[o + 2 * TPB], y3 = b[o + 3 * TPB];
            acc ^= x0.x ^ x0.y ^ x0.z ^ x0.w ^ x1.x ^ x1.y ^ x1.z ^ x1.w
                 ^ x2.x ^ x2.y ^ x2.z ^ x2.w ^ x3.x ^ x3.y ^ x3.z ^ x3.w
                 ^ y0.x ^ y0.y ^ y0.z ^ y0.w ^ y1.x ^ y1.y ^ y1.z ^ y1.w
                 ^ y2.x ^ y2.y ^ y2.z ^ y2.w ^ y3.x ^ y3.y ^ y3.z ^ y3.w;
        }
    }
    #pragma unroll
    for (int off = 32; off; off >>= 1) acc ^= __shfl_down(acc, off, 64);
    if ((threadIdx.x & 63) == 0) atomicXor(&ws[320 + (blockIdx.x & 31)], acc);
}

// ---------------- MAIN ----------------
__device__ __forceinline__ void rd_acc(float x, int lab,
                                       u64& c64, u64& p64, u32* __restrict__ cacc) {
    float e = __expf(-x);
    float conf = __builtin_amdgcn_rcpf(1.0f + e);          // sigmoid
    // bins are (l,u]: b = clip(ceil(conf*10)-1, 0, 9) == min(9, trunc(conf*10 - eps))
    float t10 = __builtin_fmaf(conf, 10.0f, -1e-6f);
    int b = min(9, (int)t10);                              // conf>0 -> t10 > -1e-6 -> >=0
    u32 cfx = (u32)__builtin_fmaf(conf, 65536.0f, 0.5f);

    u32 sh = (u32)(b * 6);                                 // 6-bit fields x 10 bins
    c64 += 1ull << sh;
    p64 += ((u64)(u32)lab) << sh;
    #pragma unroll
    for (int k = 0; k < NB; ++k)
        cacc[k] += (b == k) ? cfx : 0u;
}

__global__ __launch_bounds__(TPB) void rd_hist(const float* __restrict__ logits,
                                               const int* __restrict__ labels,
                                               u32* __restrict__ ws,
                                               long long n) {
    u32 cp[NB], cacc[NB];                                  // cp: cnt low16 | pos high16
    #pragma unroll
    for (int b = 0; b < NB; ++b) { cp[b] = 0u; cacc[b] = 0u; }

    const float4* l4 = (const float4*)logits;
    const int4*   i4 = (const int4*)labels;
    long long n4 = n >> 2;

    long long seg_begin = (long long)blockIdx.x * F4_PER_BLOCK;
    if (seg_begin + F4_PER_BLOCK <= n4) {
        long long base = seg_begin + threadIdx.x;
        #pragma unroll
        for (int s = 0; s < 4; ++s) {
            long long o = base + (long long)s * (4 * TPB);
            float4 x0 = l4[o], x1 = l4[o + TPB], x2 = l4[o + 2 * TPB], x3 = l4[o + 3 * TPB];
            int4   y0 = i4[o], y1 = i4[o + TPB], y2 = i4[o + 2 * TPB], y3 = i4[o + 3 * TPB];
            u64 c64 = 0, p64 = 0;
            rd_acc(x0.x, y0.x, c64, p64, cacc); rd_acc(x0.y, y0.y, c64, p64, cacc);
            rd_acc(x0.z, y0.z, c64, p64, cacc); rd_acc(x0.w, y0.w, c64, p64, cacc);
            rd_acc(x1.x, y1.x, c64, p64, cacc); rd_acc(x1.y, y1.y, c64, p64, cacc);
            rd_acc(x1.z, y1.z, c64, p64, cacc); rd_acc(x1.w, y1.w, c64, p64, cacc);
            rd_acc(x2.x, y2.x, c64, p64, cacc); rd_acc(x2.y, y2.y, c64, p64, cacc);
            rd_acc(x2.z, y2.z, c64, p64, cacc); rd_acc(x2.w, y2.w, c64, p64, cacc);
            rd_acc(x3.x, y3.x, c64, p64, cacc); rd_acc(x3.y, y3.y, c64, p64, cacc);
            rd_acc(x3.z, y3.z, c64, p64, cacc); rd_acc(x3.w, y3.w, c64, p64, cacc);
            #pragma unroll
            for (int b = 0; b < NB; ++b)       // 16 elems: 6-bit fields <= 16, safe
                cp[b] += ((u32)(c64 >> (6 * b)) & 63u) | ((((u32)(p64 >> (6 * b))) & 63u) << 16);
        }
    }

    // generic remainder (empty at N=2^25)
    long long covered = min(n4, (long long)gridDim.x * F4_PER_BLOCK);
    long long tid    = (long long)blockIdx.x * blockDim.x + threadIdx.x;
    long long stride = (long long)gridDim.x * blockDim.x;
    for (long long i = covered + tid; i < n4; i += stride) {
        float4 x = l4[i]; int4 y = i4[i];
        u64 c64 = 0, p64 = 0;
        rd_acc(x.x, y.x, c64, p64, cacc); rd_acc(x.y, y.y, c64, p64, cacc);
        rd_acc(x.z, y.z, c64, p64, cacc); rd_acc(x.w, y.w, c64, p64, cacc);
        #pragma unroll
        for (int b = 0; b < NB; ++b)
            cp[b] += ((u32)(c64 >> (6 * b)) & 63u) | ((((u32)(p64 >> (6 * b))) & 63u) << 16);
    }
    long long rem = n4 << 2;
    if (rem + tid < n) {
        u64 c64 = 0, p64 = 0;
        rd_acc(logits[rem + tid], labels[rem + tid], c64, p64, cacc);
        #pragma unroll
        for (int b = 0; b < NB; ++b)
            cp[b] += ((u32)(c64 >> (6 * b)) & 63u) | ((((u32)(p64 >> (6 * b))) & 63u) << 16);
    }

    // wave reduce: cp fields (<=2048 per wave) stay 16-bit safe
    __shared__ u32 s_cp[4][NB];
    __shared__ u32 s_cf[4][NB];
    int lane = threadIdx.x & 63;
    int wave = threadIdx.x >> 6;
    #pragma unroll
    for (int b = 0; b < NB; ++b) {
        u32 c = cp[b];
        u32 f = cacc[b];
        #pragma unroll
        for (int off = 32; off; off >>= 1) {
            c += __shfl_down(c, off, 64);
            f += __shfl_down(f, off, 64);
        }
        if (lane == 0) { s_cp[wave][b] = c; s_cf[wave][b] = f; }
    }
    __syncthreads();

    if (threadIdx.x < NB) {
        int b = threadIdx.x;
        u32 c = s_cp[0][b] + s_cp[1][b] + s_cp[2][b] + s_cp[3][b];   // fields <= 8192
        u64 f = (u64)s_cf[0][b] + s_cf[1][b] + s_cf[2][b] + s_cf[3][b];
        atomicAdd((u64*)&ws[32 * b], f);            // conf sum (own cache line per bin)
        atomicAdd(&ws[32 * b + 2], c & 0xFFFFu);    // count
        atomicAdd(&ws[32 * b + 3], c >> 16);        // positives
    }
}

__global__ void rd_finalize(const u32* __restrict__ ws, float* __restrict__ out) {
    int b = threadIdx.x;
    if (b < NB) {
        u64 f = *(const u64*)&ws[32 * b];
        float cnt = (float)ws[32 * b + 2];
        float sp  = (float)ws[32 * b + 3];
        float sc  = (float)((double)f * (1.0 / 65536.0));
        float denom = fmaxf(cnt, 1.0f);
        bool ne = cnt > 0.0f;
        out[b]      = ne ? (sp / denom) : 0.0f;
        out[NB + b] = ne ? (sc / denom) : 0.0f;
    }
}

extern "C" void kernel_launch(void* const* d_in, const int* in_sizes, int n_in,
                              void* d_out, int out_size, void* d_ws, size_t ws_size,
                              hipStream_t stream) {
    const float* logits = (const float*)d_in[0];
    const int*   labels = (const int*)d_in[1];
    float* out = (float*)d_out;
    u32*   ws  = (u32*)d_ws;
    long long n = (long long)in_sizes[0];

    rd_zero_ws<<<1, 512, 0, stream>>>(ws);
    // DIAGNOSTIC: identical access pattern, trivial compute. Counters separate
    // "memory-pattern floor" from "VALU/issue bound". Remove next round.
    rd_probe<<<BLOCKS, TPB, 0, stream>>>((const uint4*)logits, (const uint4*)labels, ws, n >> 2);
    rd_hist<<<BLOCKS, TPB, 0, stream>>>(logits, labels, ws, n);
    rd_finalize<<<1, 64, 0, stream>>>(ws, out);
}

// Round 7
// 342.507 us; speedup vs baseline: 1.1047x; 1.1047x over previous
//
#include <hip/hip_runtime.h>

typedef unsigned int u32;
typedef unsigned long long u64;

#define NB 10
#define BLOCKS 4096
#define TPB 256
#define F4B 2048     // float4 per block: 4096*2048 = 2^23 = N/4

// ws layout: bin b owns cache line at u32 index 32*b:
//   [32b+0..1] u64 sum(ffx), [32b+2] count, [32b+3] positives
__global__ void rd_zero_ws(u32* __restrict__ ws) {
    if (threadIdx.x < 320) ws[threadIdx.x] = 0u;
}

// Per element: sigmoid -> bin -> 4 packed u64 register accumulators. No memory ops.
__device__ __forceinline__ void rd_acc(float x, int lab,
                                       u64& c64, u64& p64, u64& flo, u64& fhi) {
    float e = __expf(-x);
    float conf = __builtin_amdgcn_rcpf(1.0f + e);        // sigmoid
    float t10 = __builtin_fmaf(conf, 10.0f, -1e-6f);     // bins are (l,u]
    int b = min(9, (int)t10);                            // t10 >= -1e-6 -> (int) >= 0
    float frac = t10 - (float)b;                         // in [0,1)
    u32 ffx = (u32)__builtin_fmaf(frac, 127.0f, 0.5f);   // 7-bit fixed point, <=127

    u32 sh6 = (u32)(b * 6);
    c64 += 1ull << sh6;                                  // count, 6-bit fields
    p64 += ((u64)(u32)lab) << sh6;                       // positives, 6-bit fields

    bool lo = b < 5;
    u32 sh12 = (u32)(b * 12);
    u32 shf = lo ? sh12 : (sh12 - 60u);
    u64 v = ((u64)ffx) << shf;                           // 12-bit fields, 5 per u64
    flo += lo ? v : 0ull;
    fhi += lo ? 0ull : v;
}

__device__ __forceinline__ void rd_acc4(const float4& x, const int4& y,
                                        u64& c64, u64& p64, u64& flo, u64& fhi) {
    rd_acc(x.x, y.x, c64, p64, flo, fhi);
    rd_acc(x.y, y.y, c64, p64, flo, fhi);
    rd_acc(x.z, y.z, c64, p64, flo, fhi);
    rd_acc(x.w, y.w, c64, p64, flo, fhi);
}

__global__ __launch_bounds__(TPB) void rd_hist(const float* __restrict__ logits,
                                               const int* __restrict__ labels,
                                               u32* __restrict__ ws,
                                               long long n) {
    u64 c64 = 0, p64 = 0, flo = 0, fhi = 0;

    const float4* l4 = (const float4*)logits;
    const int4*   i4 = (const int4*)labels;
    long long n4  = n >> 2;
    long long seg = (long long)blockIdx.x * F4B;

    if (seg + F4B <= n4) {
        long long o = seg + threadIdx.x;
        // ---- issue ALL 16 loads before any compute (16-deep MLP) ----
        float4 x0 = l4[o            ]; int4 y0 = i4[o            ];
        float4 x1 = l4[o + 1 * TPB  ]; int4 y1 = i4[o + 1 * TPB  ];
        float4 x2 = l4[o + 2 * TPB  ]; int4 y2 = i4[o + 2 * TPB  ];
        float4 x3 = l4[o + 3 * TPB  ]; int4 y3 = i4[o + 3 * TPB  ];
        float4 x4 = l4[o + 4 * TPB  ]; int4 y4 = i4[o + 4 * TPB  ];
        float4 x5 = l4[o + 5 * TPB  ]; int4 y5 = i4[o + 5 * TPB  ];
        float4 x6 = l4[o + 6 * TPB  ]; int4 y6 = i4[o + 6 * TPB  ];
        float4 x7 = l4[o + 7 * TPB  ]; int4 y7 = i4[o + 7 * TPB  ];
#if defined(__has_builtin)
#if __has_builtin(__builtin_amdgcn_sched_barrier)
        __builtin_amdgcn_sched_barrier(0);   // pin loads above compute
#endif
#endif
        rd_acc4(x0, y0, c64, p64, flo, fhi);
        rd_acc4(x1, y1, c64, p64, flo, fhi);
        rd_acc4(x2, y2, c64, p64, flo, fhi);
        rd_acc4(x3, y3, c64, p64, flo, fhi);
        rd_acc4(x4, y4, c64, p64, flo, fhi);
        rd_acc4(x5, y5, c64, p64, flo, fhi);
        rd_acc4(x6, y6, c64, p64, flo, fhi);
        rd_acc4(x7, y7, c64, p64, flo, fhi);
    }

    // ---- generic tail (empty at N=2^25): direct global atomics, runs never ----
    long long covered = (long long)gridDim.x * F4B * 4;
    if (covered < n) {
        long long tid    = (long long)blockIdx.x * blockDim.x + threadIdx.x;
        long long stride = (long long)gridDim.x * blockDim.x;
        for (long long i = covered + tid; i < n; i += stride) {
            float e = __expf(-logits[i]);
            float conf = __builtin_amdgcn_rcpf(1.0f + e);
            float t10 = __builtin_fmaf(conf, 10.0f, -1e-6f);
            int b = min(9, (int)t10);
            float frac = t10 - (float)b;
            u32 ffx = (u32)__builtin_fmaf(frac, 127.0f, 0.5f);
            atomicAdd((u64*)&ws[32 * b], (u64)ffx);
            atomicAdd(&ws[32 * b + 2], 1u);
            atomicAdd(&ws[32 * b + 3], (u32)labels[i]);
        }
    }

    // ---- unpack + wave reduce + block combine ----
    __shared__ u32 s_cp[4][NB];
    __shared__ u32 s_cf[4][NB];
    int lane = threadIdx.x & 63;
    int wave = threadIdx.x >> 6;
    #pragma unroll
    for (int b = 0; b < NB; ++b) {
        u32 cnt = (u32)(c64 >> (6 * b)) & 63u;
        u32 pos = (u32)(p64 >> (6 * b)) & 63u;
        u32 cf  = (b < 5) ? ((u32)(flo >> (12 * b)) & 4095u)
                          : ((u32)(fhi >> (12 * (b - 5))) & 4095u);
        u32 cp = cnt | (pos << 16);            // wave sums <= 2048 -> 16-bit safe
        #pragma unroll
        for (int off = 32; off; off >>= 1) {
            cp += __shfl_down(cp, off, 64);
            cf += __shfl_down(cf, off, 64);
        }
        if (lane == 0) { s_cp[wave][b] = cp; s_cf[wave][b] = cf; }
    }
    __syncthreads();

    if (threadIdx.x < NB) {
        int b = threadIdx.x;
        u32 cp = s_cp[0][b] + s_cp[1][b] + s_cp[2][b] + s_cp[3][b];   // fields <= 8192
        u64 cf = (u64)s_cf[0][b] + s_cf[1][b] + s_cf[2][b] + s_cf[3][b];
        atomicAdd((u64*)&ws[32 * b], cf);
        atomicAdd(&ws[32 * b + 2], cp & 0xFFFFu);
        atomicAdd(&ws[32 * b + 3], cp >> 16);
    }
}

__global__ void rd_finalize(const u32* __restrict__ ws, float* __restrict__ out) {
    int b = threadIdx.x;
    if (b < NB) {
        u64 f   = *(const u64*)&ws[32 * b];
        u32 cnt = ws[32 * b + 2];
        u32 pos = ws[32 * b + 3];
        // conf = (b + frac)/10, frac ~= ffx/127
        double sumconf = ((double)b * (double)cnt + (double)f * (1.0 / 127.0)) * 0.1;
        float denom = fmaxf((float)cnt, 1.0f);
        bool ne = cnt > 0u;
        out[b]      = ne ? ((float)pos / denom) : 0.0f;
        out[NB + b] = ne ? (float)(sumconf / (double)denom) : 0.0f;
    }
}

extern "C" void kernel_launch(void* const* d_in, const int* in_sizes, int n_in,
                              void* d_out, int out_size, void* d_ws, size_t ws_size,
                              hipStream_t stream) {
    const float* logits = (const float*)d_in[0];
    const int*   labels = (const int*)d_in[1];
    float* out = (float*)d_out;
    u32*   ws  = (u32*)d_ws;
    long long n = (long long)in_sizes[0];

    rd_zero_ws<<<1, 512, 0, stream>>>(ws);
    rd_hist<<<BLOCKS, TPB, 0, stream>>>(logits, labels, ws, n);
    rd_finalize<<<1, 64, 0, stream>>>(ws, out);
}

// Round 8
// 294.840 us; speedup vs baseline: 1.2832x; 1.1617x over previous
//
#include <hip/hip_runtime.h>

typedef unsigned int u32;
typedef unsigned long long u64;

#define NB 10
#define BLOCKS 2048
#define TPB 256           // 4 waves
#define ITERS 8
#define CHUNK_F4 128      // float4 per wave per iteration
#define WAVE_F4 (ITERS * CHUNK_F4)   // 1024 contiguous float4 per wave

typedef __attribute__((address_space(3))) char lds_char;
typedef __attribute__((address_space(1))) const char g_char;

__device__ __forceinline__ void dma16(const void* g, void* l) {
    // async global->LDS, 16 B/lane: LDS dest = wave-uniform base + lane*16
    __builtin_amdgcn_global_load_lds((g_char*)g, (lds_char*)l, 16, 0, 0);
}

// gfx9 waitcnt encoding: vmcnt[3:0]|[15:14], expcnt[6:4], lgkmcnt[11:8]
#define WAIT_VM(nn)  __builtin_amdgcn_s_waitcnt(((nn) & 15) | 0xF70)  // lgkm/exp don't-care
#define WAIT_LGKM0() __builtin_amdgcn_s_waitcnt(0xC07F)               // vm don't-care, lgkm=0

#if defined(__has_builtin)
#if __has_builtin(__builtin_amdgcn_sched_barrier)
#define SCHEDB() __builtin_amdgcn_sched_barrier(0)
#else
#define SCHEDB()
#endif
#else
#define SCHEDB()
#endif

// ws layout: bin b owns cache line at u32 index 32*b:
//   [32b+0..1] u64 sum(ffx), [32b+2] count, [32b+3] positives
__global__ void rd_zero_ws(u32* __restrict__ ws) {
    if (threadIdx.x < 320) ws[threadIdx.x] = 0u;
}

// Per element: sigmoid -> bin -> 4 packed u64 register accumulators.
__device__ __forceinline__ void rd_acc(float x, int lab,
                                       u64& c64, u64& p64, u64& flo, u64& fhi) {
    float e = __expf(-x);
    float conf = __builtin_amdgcn_rcpf(1.0f + e);        // sigmoid
    float t10 = __builtin_fmaf(conf, 10.0f, -1e-6f);     // bins are (l,u]
    int b = min(9, (int)t10);
    float frac = t10 - (float)b;                         // [0,1)
    u32 ffx = (u32)__builtin_fmaf(frac, 127.0f, 0.5f);   // 7-bit fixed point

    u32 sh6 = (u32)(b * 6);
    c64 += 1ull << sh6;                                  // 6-bit count fields
    p64 += ((u64)(u32)lab) << sh6;                       // 6-bit positive fields

    bool lo = b < 5;
    u32 sh12 = (u32)(b * 12);
    u32 shf = lo ? sh12 : (sh12 - 60u);
    u64 v = ((u64)ffx) << shf;                           // 12-bit fields, 5 per u64
    flo += lo ? v : 0ull;
    fhi += lo ? 0ull : v;
}

__device__ __forceinline__ void rd_acc4(const float4& x, const int4& y,
                                        u64& c64, u64& p64, u64& flo, u64& fhi) {
    rd_acc(x.x, y.x, c64, p64, flo, fhi);
    rd_acc(x.y, y.y, c64, p64, flo, fhi);
    rd_acc(x.z, y.z, c64, p64, flo, fhi);
    rd_acc(x.w, y.w, c64, p64, flo, fhi);
}

__global__ __launch_bounds__(TPB) void rd_hist(const float* __restrict__ logits,
                                               const int* __restrict__ labels,
                                               u32* __restrict__ ws,
                                               long long n) {
    // per wave 8 KB: buf{0,1} x (2 KB logits + 2 KB labels); 4 waves = 32 KB
    __shared__ __align__(16) char lds[32 * 1024];

    u32 cp[NB], cf[NB];
    #pragma unroll
    for (int b = 0; b < NB; ++b) { cp[b] = 0u; cf[b] = 0u; }

    const float4* l4 = (const float4*)logits;
    const int4*   i4 = (const int4*)labels;
    int lane = threadIdx.x & 63;
    int wave = threadIdx.x >> 6;
    long long nf4 = n >> 2;
    long long seg = (long long)blockIdx.x * (4 * WAVE_F4);

    if (seg + 4 * WAVE_F4 <= nf4) {
        long long gb = seg + (long long)wave * WAVE_F4;
        const float4* gl = l4 + gb + lane;
        const int4*   gi = i4 + gb + lane;
        char* myl = lds + wave * 8192;

        #define ISSUE(t, bb) do {                               \
            char* _base = myl + (bb) * 4096;                    \
            dma16(gl + (t) * CHUNK_F4,      _base);             \
            dma16(gl + (t) * CHUNK_F4 + 64, _base + 1024);      \
            dma16(gi + (t) * CHUNK_F4,      _base + 2048);      \
            dma16(gi + (t) * CHUNK_F4 + 64, _base + 3072);      \
        } while (0)

        ISSUE(0, 0);
        ISSUE(1, 1);

        u64 c64 = 0, p64 = 0, flo = 0, fhi = 0;
        #pragma unroll
        for (int t = 0; t < ITERS; ++t) {
            const int bb = t & 1;
            const char* base = myl + bb * 4096;
            if (t < ITERS - 1) { WAIT_VM(4); } else { WAIT_VM(0); }
            SCHEDB();
            float4 xa = *(const float4*)(base + lane * 16);
            float4 xb = *(const float4*)(base + 1024 + lane * 16);
            int4   ya = *(const int4*)(base + 2048 + lane * 16);
            int4   yb = *(const int4*)(base + 3072 + lane * 16);
            WAIT_LGKM0();                 // reads landed in VGPRs -> buffer reusable
            SCHEDB();
            if (t + 2 < ITERS) ISSUE(t + 2, bb);
            SCHEDB();
            rd_acc4(xa, ya, c64, p64, flo, fhi);
            rd_acc4(xb, yb, c64, p64, flo, fhi);
            if ((t & 3) == 3) {           // unpack every 32 elems (field-safe)
                #pragma unroll
                for (int b = 0; b < NB; ++b) {
                    u32 cnt = (u32)(c64 >> (6 * b)) & 63u;
                    u32 pos = (u32)(p64 >> (6 * b)) & 63u;
                    cp[b] += cnt | (pos << 16);
                    cf[b] += (b < 5) ? ((u32)(flo >> (12 * b)) & 4095u)
                                     : ((u32)(fhi >> (12 * (b - 5))) & 4095u);
                }
                c64 = 0; p64 = 0; flo = 0; fhi = 0;
            }
        }
        #undef ISSUE
    }

    // generic tail (empty at N=2^25): direct atomics, rarely runs
    long long done_f4 = ((long long)gridDim.x < nf4 / (4 * WAVE_F4)
                             ? (long long)gridDim.x
                             : nf4 / (4 * WAVE_F4)) * (4 * WAVE_F4);
    long long tail = done_f4 * 4;
    if (tail < n) {
        long long tid    = (long long)blockIdx.x * blockDim.x + threadIdx.x;
        long long stride = (long long)gridDim.x * blockDim.x;
        for (long long i = tail + tid; i < n; i += stride) {
            float e = __expf(-logits[i]);
            float conf = __builtin_amdgcn_rcpf(1.0f + e);
            float t10 = __builtin_fmaf(conf, 10.0f, -1e-6f);
            int b = min(9, (int)t10);
            float frac = t10 - (float)b;
            u32 ffx = (u32)__builtin_fmaf(frac, 127.0f, 0.5f);
            atomicAdd((u64*)&ws[32 * b], (u64)ffx);
            atomicAdd(&ws[32 * b + 2], 1u);
            atomicAdd(&ws[32 * b + 3], (u32)labels[i]);
        }
    }

    // wave reduce + block combine
    __shared__ u32 s_cp[4][NB];
    __shared__ u32 s_cf[4][NB];
    #pragma unroll
    for (int b = 0; b < NB; ++b) {
        u32 c = cp[b];                      // thread sums <= 64 -> 16-bit safe
        u32 f = cf[b];
        #pragma unroll
        for (int off = 32; off; off >>= 1) {
            c += __shfl_down(c, off, 64);
            f += __shfl_down(f, off, 64);
        }
        if (lane == 0) { s_cp[wave][b] = c; s_cf[wave][b] = f; }
    }
    __syncthreads();

    if (threadIdx.x < NB) {
        int b = threadIdx.x;
        u32 c = s_cp[0][b] + s_cp[1][b] + s_cp[2][b] + s_cp[3][b];  // fields <= 16384
        u64 f = (u64)s_cf[0][b] + s_cf[1][b] + s_cf[2][b] + s_cf[3][b];
        atomicAdd((u64*)&ws[32 * b], f);
        atomicAdd(&ws[32 * b + 2], c & 0xFFFFu);
        atomicAdd(&ws[32 * b + 3], c >> 16);
    }
}

__global__ void rd_finalize(const u32* __restrict__ ws, float* __restrict__ out) {
    int b = threadIdx.x;
    if (b < NB) {
        u64 f   = *(const u64*)&ws[32 * b];
        u32 cnt = ws[32 * b + 2];
        u32 pos = ws[32 * b + 3];
        double sumconf = ((double)b * (double)cnt + (double)f * (1.0 / 127.0)) * 0.1;
        float denom = fmaxf((float)cnt, 1.0f);
        bool ne = cnt > 0u;
        out[b]      = ne ? ((float)pos / denom) : 0.0f;
        out[NB + b] = ne ? (float)(sumconf / (double)denom) : 0.0f;
    }
}

extern "C" void kernel_launch(void* const* d_in, const int* in_sizes, int n_in,
                              void* d_out, int out_size, void* d_ws, size_t ws_size,
                              hipStream_t stream) {
    const float* logits = (const float*)d_in[0];
    const int*   labels = (const int*)d_in[1];
    float* out = (float*)d_out;
    u32*   ws  = (u32*)d_ws;
    long long n = (long long)in_sizes[0];

    rd_zero_ws<<<1, 512, 0, stream>>>(ws);
    rd_hist<<<BLOCKS, TPB, 0, stream>>>(logits, labels, ws, n);
    rd_finalize<<<1, 64, 0, stream>>>(ws, out);
}